// Round 8
// baseline (247.140 us; speedup 1.0000x reference)
//
#include <hip/hip_runtime.h>

// TextCNN: B=128, S=512, E=300, H=64, k_i = i/2+2 in [2,33].
// Virtual-im2col GEMM on mfma_f32_32x32x16_bf16, N-groups of 32 filters.
//   Grid: 128 b x 4 slices (128 rows) = 512 blocks x 4 waves, 52.5 KB LDS, 2 blk/CU.
//   Wave (pair, q): pair owns 2 tiles of 32 rows; q = u-half of K (5 of 10 substeps).
//   Sequential E-halves staged in LDS (160 half-rows x 168-elem pitch).
//   Pair reduction via LDS at end; epilogue tanh + masked max on even waves.
//   Groups: hi = filters 32..63 (kmax 33, 330 steps/half), lo = 0..31 (170/half).
//   FIX vs r5: epilogue accumulates mx across BOTH t-tiles before the single
//   wsF write (r5 wrote inside the t-loop -> only last tile's max survived;
//   same bug class as r6, confirmed by r6->r7 fix).
// ws: [0,1MB) wsB bf16 (1000 frags x 512) | [2MB,+256KB) wsF f32 (128*64*8).

#define SS  512
#define EE  300
#define HH  64
#define LP  168            // LDS half-row pitch (336 B, 16B-aligned for b128)

typedef __attribute__((ext_vector_type(8)))  short bf16x8;
typedef __attribute__((ext_vector_type(16))) float f32x16;

__device__ __forceinline__ unsigned short f2bf(float f) {
    unsigned u = __float_as_uint(f);
    unsigned r = ((u >> 16) & 1u) + 0x7FFFu;   // RNE
    return (unsigned short)((u + r) >> 16);
}

// ---- Kernel 1: repack Wconv (f32 [64][33][300]) -> wsB bf16, 32x32x16 B-frag order.
// frag id: kh*500 + (hi: j*10+u | lo: 330 + j*10+u). elem: frag*512 + lane*8 + r.
// B-frag: n = lane&31 (filter in group), k = (lane>>5)*8 + r; e = kh*160 + u*16 + k.
__global__ __launch_bounds__(256) void prep_weights(const float* __restrict__ Wconv,
                                                    unsigned short* __restrict__ wsB) {
    int idx = blockIdx.x * 256 + threadIdx.x;      // < 512000
    int r    = idx & 7;
    int lane = (idx >> 3) & 63;
    int frag = idx >> 9;                           // < 1000
    int kh = frag / 500;
    int fr = frag - kh * 500;
    int j, u, i;
    if (fr < 330) { j = fr / 10; u = fr - j * 10; i = 32 + (lane & 31); }
    else { int t = fr - 330; j = t / 10; u = t - j * 10; i = lane & 31; }
    int ki = i / 2 + 2;
    int kk = (lane >> 5) * 8 + r;
    int e  = kh * 160 + u * 16 + kk;
    float v = 0.f;
    if (e < EE && j < ki) v = Wconv[(i * 33 + j) * EE + e];
    wsB[idx] = f2bf(v);
}

#define MFMA32(A, B, C) __builtin_amdgcn_mfma_f32_32x32x16_bf16((A), (B), (C), 0, 0, 0)

template<bool LO>
__device__ __forceinline__ void step32(const unsigned short* At, int rowb, int j, int u,
                                       const unsigned short* __restrict__ bb,
                                       int n, int hi, f32x16 acc[2][2]) {
    const unsigned short* ar = At + (rowb + n + j) * LP + u * 16 + hi * 8;
    bf16x8 a0 = *(const bf16x8*)ar;
    bf16x8 a1 = *(const bf16x8*)(ar + 32 * LP);
    bf16x8 bh = *(const bf16x8*)(bb + (j * 10 + u) * 512);
    acc[0][0] = MFMA32(a0, bh, acc[0][0]);
    acc[1][0] = MFMA32(a1, bh, acc[1][0]);
    if (LO) {
        bf16x8 bl = *(const bf16x8*)(bb + (330 + j * 10 + u) * 512);
        acc[0][1] = MFMA32(a0, bl, acc[0][1]);
        acc[1][1] = MFMA32(a1, bl, acc[1][1]);
    }
}

// ---- Kernel 2: fused gather + GEMM + tanh + masked max. 512 blocks x 256 thr.
__global__ __launch_bounds__(256, 2) void conv_fused(const int* __restrict__ x,
                                                     const float* __restrict__ emb,
                                                     const unsigned short* __restrict__ wsB,
                                                     const float* __restrict__ bconv,
                                                     float* __restrict__ wsF) {
    __shared__ __align__(16) unsigned short At[160 * LP];   // 52.5 KB

    int b     = blockIdx.x >> 2;
    int slice = blockIdx.x & 3;
    int t0    = slice * 128;

    int lane = threadIdx.x & 63;
    int w    = threadIdx.x >> 6;
    int pair = w >> 1;                 // owns tiles {pair*64, pair*64+32}
    int q    = w & 1;                  // u-half: u in [q*5, q*5+5)
    int n  = lane & 31;
    int hi = lane >> 5;
    int rowb = pair * 64;

    f32x16 acc[2][2] = {};             // [tile][group: 0=hi(filters 32..63), 1=lo]

    for (int eh = 0; eh < 2; ++eh) {
        if (eh) __syncthreads();
        // Stage 160 half-rows (128 + 32 halo), f32 -> bf16, zero-padded.
        #pragma unroll
        for (int it = 0; it < 13; ++it) {
            int idx = threadIdx.x + it * 256;
            if (idx < 3200) {
                int rr = idx / 20, c = idx - rr * 20;
                int srow = t0 + rr;
                bf16x8 v = {0, 0, 0, 0, 0, 0, 0, 0};
                if (srow < SS) {
                    int tok = x[b * SS + srow];
                    const float* ep = emb + (long)tok * EE + eh * 160 + c * 8;
                    if (eh == 0 || c < 17) {
                        float4 f0 = ((const float4*)ep)[0];
                        float4 f1 = ((const float4*)ep)[1];
                        v[0] = f2bf(f0.x); v[1] = f2bf(f0.y); v[2] = f2bf(f0.z); v[3] = f2bf(f0.w);
                        v[4] = f2bf(f1.x); v[5] = f2bf(f1.y); v[6] = f2bf(f1.z); v[7] = f2bf(f1.w);
                    } else if (c == 17) {       // elems 296..299
                        float4 f0 = ((const float4*)ep)[0];
                        v[0] = f2bf(f0.x); v[1] = f2bf(f0.y); v[2] = f2bf(f0.z); v[3] = f2bf(f0.w);
                    }
                }
                *(bf16x8*)&At[rr * LP + c * 8] = v;
            }
        }
        __syncthreads();

        const unsigned short* bb = wsB + (size_t)eh * 256000 + lane * 8;
        int u0 = q * 5;
        #pragma unroll 1
        for (int j = 0; j < 17; ++j) {
            #pragma unroll
            for (int u5 = 0; u5 < 5; ++u5) step32<true >(At, rowb, j, u0 + u5, bb, n, hi, acc);
        }
        #pragma unroll 1
        for (int j = 17; j < 33; ++j) {
            #pragma unroll
            for (int u5 = 0; u5 < 5; ++u5) step32<false>(At, rowb, j, u0 + u5, bb, n, hi, acc);
        }
    }

    // Pair K-reduction via LDS (lane-contiguous layout: conflict-free).
    __syncthreads();
    float* red = (float*)At;
    if (q == 1) {
        #pragma unroll
        for (int t = 0; t < 2; ++t)
            #pragma unroll
            for (int g = 0; g < 2; ++g)
                #pragma unroll
                for (int r = 0; r < 16; ++r)
                    red[((t * 2 + g) * 16 + r) * 128 + pair * 64 + lane] = acc[t][g][r];
    }
    __syncthreads();
    if (q == 0) {
        #pragma unroll
        for (int t = 0; t < 2; ++t)
            #pragma unroll
            for (int g = 0; g < 2; ++g)
                #pragma unroll
                for (int r = 0; r < 16; ++r)
                    acc[t][g][r] += red[((t * 2 + g) * 16 + r) * 128 + pair * 64 + lane];

        // Epilogue. 32x32 C/D (HW-verified): col = lane&31,
        // row = (r&3) + 8*(r>>2) + 4*(lane>>5).
        // g outer, t inner: ONE wsF write per g, max over BOTH tiles.
        #pragma unroll
        for (int g = 0; g < 2; ++g) {
            int i  = (g == 0) ? 32 + n : n;
            int ki = i / 2 + 2;
            int tmax = SS - ki;
            float bc = bconv[i];
            float mx = -3.0e38f;
            #pragma unroll
            for (int t = 0; t < 2; ++t) {
                #pragma unroll
                for (int r = 0; r < 16; ++r) {
                    int row = (r & 3) + 8 * (r >> 2) + 4 * hi;
                    int tt  = t0 + pair * 64 + t * 32 + row;
                    float v = tanhf(acc[t][g][r] + bc);
                    if (tt <= tmax) mx = fmaxf(mx, v);
                }
            }
            mx = fmaxf(mx, __shfl_xor(mx, 32));
            if (hi == 0) wsF[(b * HH + i) * 8 + slice * 2 + pair] = mx;
        }
    }
}

// ---- Kernel 3: max over 8 partials, linear, sigmoid. 128 blocks x 64 thr.
__global__ __launch_bounds__(64) void final_linear(const float* __restrict__ wsF,
                                                   const float* __restrict__ Wlin,
                                                   const float* __restrict__ blin,
                                                   float* __restrict__ out) {
    int b = blockIdx.x;
    int i = threadIdx.x;
    const float4* pp = (const float4*)(wsF + (b * HH + i) * 8);
    float4 f0 = pp[0], f1 = pp[1];
    float mx = fmaxf(fmaxf(fmaxf(f0.x, f0.y), fmaxf(f0.z, f0.w)),
                     fmaxf(fmaxf(f1.x, f1.y), fmaxf(f1.z, f1.w)));
    float v = mx * Wlin[i];
    #pragma unroll
    for (int off = 1; off < 64; off <<= 1) v += __shfl_xor(v, off);
    if (i == 0) out[b] = 1.0f / (1.0f + expf(-(v + blin[0])));
}

extern "C" void kernel_launch(void* const* d_in, const int* in_sizes, int n_in,
                              void* d_out, int out_size, void* d_ws, size_t ws_size,
                              hipStream_t stream) {
    const int*   x     = (const int*)d_in[0];
    const float* emb   = (const float*)d_in[1];
    const float* Wconv = (const float*)d_in[2];
    const float* bconv = (const float*)d_in[3];
    const float* Wlin  = (const float*)d_in[4];
    const float* blin  = (const float*)d_in[5];
    float* out = (float*)d_out;

    unsigned short* wsB = (unsigned short*)d_ws;
    float*          wsF = (float*)((char*)d_ws + (2u << 20));

    prep_weights<<<2000, 256, 0, stream>>>(Wconv, wsB);
    conv_fused<<<512, 256, 0, stream>>>(x, emb, wsB, bconv, wsF);
    final_linear<<<128, 64, 0, stream>>>(wsF, Wlin, blin, out);
}

// Round 9
// 215.691 us; speedup vs baseline: 1.1458x; 1.1458x over previous
//
#include <hip/hip_runtime.h>

// TextCNN: B=128, S=512, E=300, H=64, k_i = i/2+2 in [2,33].
// Virtual-im2col bf16 MFMA 16x16x32 (HW-verified layouts).
//   Grid: 128 b x 8 slices (64 rows) = 1024 blocks = 4/CU, 31.5 KB LDS,
//   __launch_bounds__(256,4) -> 16 waves/CU target.
//   All 4 waves share the block's 64 rows (4 M-tiles); K split 4-way by j mod 4.
//   Register-double-buffered B prefetch across the (j,u) step stream.
//   Cross-wave K-sum: 2-round LDS reduction (tiles {0,1} then {2,3}), q0 epilogue.
//   wsB layout identical to r4 (verified): [eh][group][j*5+u], bases {0,45,130,255}.
// ws: [0,1MB) wsB bf16 (+slack for prefetch overreach) | [2MB,+256KB) wsF f32.

#define SS     512
#define EE     300
#define HH     64
#define LP     168          // LDS half-row pitch in elems (336 B)
#define HALFSZ 215040       // wsB elems per E-half (420 frags * 512)

typedef __attribute__((ext_vector_type(8))) short bf16x8;
typedef __attribute__((ext_vector_type(4))) float f32x4;

__device__ __forceinline__ unsigned short f2bf(float f) {
    unsigned u = __float_as_uint(f);
    unsigned r = ((u >> 16) & 1u) + 0x7FFFu;   // RNE
    return (unsigned short)((u + r) >> 16);
}

// ---- Kernel 1: repack Wconv (f32 [64][33][300]) -> wsB bf16 (r4 verbatim, verified).
__global__ __launch_bounds__(256) void prep_weights(const float* __restrict__ Wconv,
                                                    unsigned short* __restrict__ wsB) {
    int idx = blockIdx.x * 256 + threadIdx.x;      // < 430080
    int r    = idx & 7;
    int lane = (idx >> 3) & 63;
    int gs   = idx >> 9;                           // < 840
    int h    = gs / 420;
    int ww   = gs - h * 420;
    int g, t;
    if      (ww < 45)  { g = 0; t = ww;       }
    else if (ww < 130) { g = 1; t = ww - 45;  }
    else if (ww < 255) { g = 2; t = ww - 130; }
    else               { g = 3; t = ww - 255; }
    int j = t / 5, u = t - j * 5;
    int i  = g * 16 + (lane & 15);
    int ki = i / 2 + 2;
    int kk = (lane >> 4) * 8 + r;
    int e  = h * 160 + u * 32 + kk;
    float v = 0.f;
    if (e < EE && j < ki) v = Wconv[(i * 33 + j) * EE + e];
    wsB[idx] = f2bf(v);
}

#define MFMA(A, Bf, C) __builtin_amdgcn_mfma_f32_16x16x32_bf16((A), (Bf), (C), 0, 0, 0)

// Band over j in [lo,hi) with j%4==q, NG groups active (slot s: 0=g3,1=g2,2=g1,3=g0).
// B register double-buffer: Bn prefetched while MFMAs consume Bc.
template<int NG>
__device__ __forceinline__ void band(int q, int lo, int hi,
                                     const unsigned short* lb,
                                     const unsigned short* __restrict__ bp,
                                     f32x4 acc[4][4]) {
    constexpr int bases[4] = {255, 130, 45, 0};
    int j0 = lo + ((q - lo) & 3);
    if (j0 >= hi) return;
    bf16x8 Bc[NG];
    #pragma unroll
    for (int s = 0; s < NG; ++s)
        Bc[s] = *(const bf16x8*)(bp + (bases[s] + j0 * 5) * 512);
    for (int j = j0; j < hi; j += 4) {
        #pragma unroll
        for (int u = 0; u < 5; ++u) {
            int fn = (u == 4) ? (j + 4) * 5 : j * 5 + u + 1;   // next step's frag
            bf16x8 Bn[NG];
            #pragma unroll
            for (int s = 0; s < NG; ++s)
                Bn[s] = *(const bf16x8*)(bp + (bases[s] + fn) * 512);
            const unsigned short* lr = lb + j * LP + u * 32;
            bf16x8 a0 = *(const bf16x8*)(lr);
            bf16x8 a1 = *(const bf16x8*)(lr + 16 * LP);
            bf16x8 a2 = *(const bf16x8*)(lr + 32 * LP);
            bf16x8 a3 = *(const bf16x8*)(lr + 48 * LP);
            #pragma unroll
            for (int s = 0; s < NG; ++s) {
                acc[0][s] = MFMA(a0, Bc[s], acc[0][s]);
                acc[1][s] = MFMA(a1, Bc[s], acc[1][s]);
                acc[2][s] = MFMA(a2, Bc[s], acc[2][s]);
                acc[3][s] = MFMA(a3, Bc[s], acc[3][s]);
            }
            #pragma unroll
            for (int s = 0; s < NG; ++s) Bc[s] = Bn[s];
        }
    }
}

// ---- Kernel 2: fused gather + GEMM + tanh + masked max. 1024 blocks x 256 thr.
__global__ __launch_bounds__(256, 4) void conv_fused(const int* __restrict__ x,
                                                     const float* __restrict__ emb,
                                                     const unsigned short* __restrict__ wsB,
                                                     const float* __restrict__ bconv,
                                                     float* __restrict__ wsF) {
    __shared__ __align__(16) unsigned short At[96 * LP];    // 31.5 KB

    int b     = blockIdx.x >> 3;
    int slice = blockIdx.x & 7;
    int t0    = slice * 64;

    int lane = threadIdx.x & 63;
    int q    = threadIdx.x >> 6;       // K-split: j % 4 == q
    int m = lane & 15, q16 = lane >> 4;

    f32x4 acc[4][4] = {};              // [tile][slot]  slot: 0=g3,1=g2,2=g1,3=g0
    const unsigned short* lb = At + m * LP + q16 * 8;

    for (int eh = 0; eh < 2; ++eh) {
        if (eh) __syncthreads();
        // Stage 96 half-rows (64 computed + 32 halo), f32 -> bf16, zero-padded.
        #pragma unroll
        for (int it = 0; it < 8; ++it) {
            int idx = threadIdx.x + it * 256;      // < 1920 = 96*20
            if (idx < 1920) {
                int rr = idx / 20, c = idx - rr * 20;
                int srow = t0 + rr;
                bf16x8 v = {0, 0, 0, 0, 0, 0, 0, 0};
                if (srow < SS) {
                    int tok = x[b * SS + srow];
                    const float* ep = emb + (long)tok * EE + eh * 160 + c * 8;
                    if (eh == 0 || c < 17) {
                        float4 f0 = ((const float4*)ep)[0];
                        float4 f1 = ((const float4*)ep)[1];
                        v[0] = f2bf(f0.x); v[1] = f2bf(f0.y); v[2] = f2bf(f0.z); v[3] = f2bf(f0.w);
                        v[4] = f2bf(f1.x); v[5] = f2bf(f1.y); v[6] = f2bf(f1.z); v[7] = f2bf(f1.w);
                    } else if (c == 17) {          // elems 296..299
                        float4 f0 = ((const float4*)ep)[0];
                        v[0] = f2bf(f0.x); v[1] = f2bf(f0.y); v[2] = f2bf(f0.z); v[3] = f2bf(f0.w);
                    }
                }
                *(bf16x8*)&At[rr * LP + c * 8] = v;
            }
        }
        __syncthreads();

        const unsigned short* bp = wsB + eh * HALFSZ + lane * 8;
        band<4>(q,  0,  9, lb, bp, acc);
        band<3>(q,  9, 17, lb, bp, acc);
        band<2>(q, 17, 25, lb, bp, acc);
        band<1>(q, 25, 33, lb, bp, acc);
    }

    // Cross-wave K-sum: waves 1..3 -> wave 0, two rounds (tiles {0,1}, {2,3}).
    float* red = (float*)At;
    #pragma unroll
    for (int rd = 0; rd < 2; ++rd) {
        __syncthreads();
        if (q != 0) {
            #pragma unroll
            for (int t2 = 0; t2 < 2; ++t2)
                #pragma unroll
                for (int s = 0; s < 4; ++s)
                    #pragma unroll
                    for (int r = 0; r < 4; ++r)
                        red[(q - 1) * 2048 + ((t2 * 4 + s) * 4 + r) * 64 + lane]
                            = acc[rd * 2 + t2][s][r];
        }
        __syncthreads();
        if (q == 0) {
            #pragma unroll
            for (int t2 = 0; t2 < 2; ++t2)
                #pragma unroll
                for (int s = 0; s < 4; ++s)
                    #pragma unroll
                    for (int r = 0; r < 4; ++r) {
                        int idx = ((t2 * 4 + s) * 4 + r) * 64 + lane;
                        acc[rd * 2 + t2][s][r] += red[idx] + red[2048 + idx] + red[4096 + idx];
                    }
        }
    }

    if (q == 0) {
        // Epilogue: C/D col = lane&15, row = q16*4 + reg (verified layout).
        // slot s -> filter group (3-s). ONE wsF write per filter, max over all 4 tiles.
        #pragma unroll
        for (int s = 0; s < 4; ++s) {
            int i  = (3 - s) * 16 + m;
            int ki = i / 2 + 2;
            int tmax = SS - ki;
            float bc = bconv[i];
            float mx = -3.0e38f;
            #pragma unroll
            for (int t = 0; t < 4; ++t) {
                int tb = t0 + t * 16 + q16 * 4;
                #pragma unroll
                for (int r = 0; r < 4; ++r) {
                    float v = tanhf(acc[t][s][r] + bc);
                    if (tb + r <= tmax) mx = fmaxf(mx, v);
                }
            }
            mx = fmaxf(mx, __shfl_xor(mx, 16));
            mx = fmaxf(mx, __shfl_xor(mx, 32));
            if (q16 == 0) wsF[(b * HH + i) * 8 + slice] = mx;
        }
    }
}

// ---- Kernel 3: max over 8 slice partials, linear, sigmoid. 128 blocks x 64 thr.
__global__ __launch_bounds__(64) void final_linear(const float* __restrict__ wsF,
                                                   const float* __restrict__ Wlin,
                                                   const float* __restrict__ blin,
                                                   float* __restrict__ out) {
    int b = blockIdx.x;
    int i = threadIdx.x;
    const float4* pp = (const float4*)(wsF + (b * HH + i) * 8);
    float4 f0 = pp[0], f1 = pp[1];
    float mx = fmaxf(fmaxf(fmaxf(f0.x, f0.y), fmaxf(f0.z, f0.w)),
                     fmaxf(fmaxf(f1.x, f1.y), fmaxf(f1.z, f1.w)));
    float v = mx * Wlin[i];
    #pragma unroll
    for (int off = 1; off < 64; off <<= 1) v += __shfl_xor(v, off);
    if (i == 0) out[b] = 1.0f / (1.0f + expf(-(v + blin[0])));
}

extern "C" void kernel_launch(void* const* d_in, const int* in_sizes, int n_in,
                              void* d_out, int out_size, void* d_ws, size_t ws_size,
                              hipStream_t stream) {
    const int*   x     = (const int*)d_in[0];
    const float* emb   = (const float*)d_in[1];
    const float* Wconv = (const float*)d_in[2];
    const float* bconv = (const float*)d_in[3];
    const float* Wlin  = (const float*)d_in[4];
    const float* blin  = (const float*)d_in[5];
    float* out = (float*)d_out;

    unsigned short* wsB = (unsigned short*)d_ws;
    float*          wsF = (float*)((char*)d_ws + (2u << 20));

    prep_weights<<<1680, 256, 0, stream>>>(Wconv, wsB);
    conv_fused<<<1024, 256, 0, stream>>>(x, emb, wsB, bconv, wsF);
    final_linear<<<128, 64, 0, stream>>>(wsF, Wlin, blin, out);
}